// Round 3
// baseline (1155.058 us; speedup 1.0000x reference)
//
#include <hip/hip_runtime.h>
#include <math.h>

// LDPC BP decoder, (3,6)-regular. 1 WG = 1 batch element, 1024 threads.
// Edge e (vn order) = 3v+j; c = e mod 8192; cn-order slot q = 6c+t, e = c+8192t.
// Thread owns CNs c = tid + 1024*i (i=0..7); messages f32 in registers.
// VN totals computed by exact-order gather via a staged LDS edge buffer:
//   edges [0,24576)  = t-blocks 0..2  -> VNs [0,8192)
//   edges [24576,49152) = t-blocks 3..5 -> VNs [8192,16384)
// Reference f32 op chain replicated literally; exp/log computed in f64 and
// rounded once to f32 (~correctly-rounded f32 primitives).

constexpr int NUM_VNS  = 16384;
constexpr int NUM_ITER = 8;
constexpr float LLR_MAX  = 20.0f;
constexpr float PHI_MIN  = 8.5e-8f;
constexpr float PHI_MAX  = 16.635532f;

#define THREADS 1024

__device__ __forceinline__ float phi_f(float x) {
    // literal: clip; ex = exp(x) [f32-rounded]; log(ex+1) - log(ex-1), each
    // add/sub and each log result f32-rounded, subtraction in f32.
    x = fminf(fmaxf(x, PHI_MIN), PHI_MAX);
    float ex = (float)::exp((double)x);
    float a  = ex + 1.0f;
    float b  = ex - 1.0f;
    float la = (float)::log((double)a);
    float lb = (float)::log((double)b);
    return la - lb;
}

__global__ __launch_bounds__(THREADS)
void ldpc_bp_kernel(const float* __restrict__ llr_ch, float* __restrict__ out)
{
    __shared__ float buf[24576];    // 96 KB: one half of the edges (3 t-blocks)
    __shared__ float vtot[NUM_VNS]; // 64 KB

    const int b   = blockIdx.x;
    const int tid = threadIdx.x;
    const float* __restrict__ llr_b = llr_ch + (size_t)b * NUM_VNS;

    // rllr[k] = -clip(llr_ch, +-20) for v = tid + 1024k  (internal sign conv)
    float rllr[16];
#pragma unroll
    for (int k = 0; k < 16; ++k) {
        float x = llr_b[tid + THREADS * k];
        x = fminf(fmaxf(x, -LLR_MAX), LLR_MAX);
        rllr[k] = -x;
    }

    float msg[6][8];   // msg[t][i] = CN->VN message on edge e = (tid+1024i) + 8192t
#pragma unroll
    for (int t = 0; t < 6; ++t)
#pragma unroll
        for (int i = 0; i < 8; ++i) msg[t][i] = 0.0f;

    for (int iter = 0; iter <= NUM_ITER; ++iter) {
        // ---- A: stage lower t-blocks (t=0..2) into buf[e] ----
#pragma unroll
        for (int t = 0; t < 3; ++t)
#pragma unroll
            for (int i = 0; i < 8; ++i)
                buf[(t << 13) + tid + THREADS * i] = msg[t][i];
        __syncthreads();

        // ---- B: vtot for v in [0,8192), exact order ((m0+m1)+m2)+llr ----
#pragma unroll
        for (int k = 0; k < 8; ++k) {
            int v = tid + THREADS * k;
            int e = 3 * v;
            float s = ((buf[e] + buf[e + 1]) + buf[e + 2]) + rllr[k];
            vtot[v] = s;
        }
        __syncthreads();

        // ---- C: stage upper t-blocks (t=3..5) ----
#pragma unroll
        for (int t = 0; t < 3; ++t)
#pragma unroll
            for (int i = 0; i < 8; ++i)
                buf[(t << 13) + tid + THREADS * i] = msg[t + 3][i];
        __syncthreads();

        // ---- D: vtot for v in [8192,16384) ----
#pragma unroll
        for (int k = 8; k < 16; ++k) {
            int v = tid + THREADS * k;
            int e = 3 * v - 24576;
            float s = ((buf[e] + buf[e + 1]) + buf[e + 2]) + rllr[k];
            vtot[v] = s;
        }
        __syncthreads();

        if (iter == NUM_ITER) break;

        // ---- E: CN update, literal reference chain ----
#pragma unroll 1
        for (int i = 0; i < 8; ++i) {
            int c = tid + THREADS * i;
            float mag[6];
            unsigned sb = 0u;
#pragma unroll
            for (int t = 0; t < 6; ++t) {
                int e = c + (t << 13);
                int v = (int)(((unsigned)e * 43691u) >> 17);   // e/3
                float m = vtot[v] - msg[t][i];                 // vn-extrinsic
                if (m < 0.0f) sb |= (1u << t);                 // sign(0) -> +1
                mag[t] = phi_f(fabsf(m));
            }
            // mag_sum in cn-edge order (sequential, with its cancellation)
            float ms = ((((mag[0] + mag[1]) + mag[2]) + mag[3]) + mag[4]) + mag[5];
            unsigned all6 = __popc(sb) & 1u;                   // sign of product
#pragma unroll
            for (int t = 0; t < 6; ++t) {
                float o = phi_f(ms - mag[t]);
                unsigned flip = all6 ^ ((sb >> t) & 1u);
                msg[t][i] = flip ? -o : o;
            }
        }
        __syncthreads();
    }

    // ---- marginalize: out[b][v] = -vtot[v] ----
#pragma unroll
    for (int k = 0; k < 16; ++k) {
        int v = tid + THREADS * k;
        out[(size_t)b * NUM_VNS + v] = -vtot[v];
    }
}

extern "C" void kernel_launch(void* const* d_in, const int* in_sizes, int n_in,
                              void* d_out, int out_size, void* d_ws, size_t ws_size,
                              hipStream_t stream) {
    const float* llr_ch = (const float*)d_in[0];
    float* out = (float*)d_out;
    ldpc_bp_kernel<<<dim3(128), dim3(THREADS), 0, stream>>>(llr_ch, out);
}

// Round 4
// 609.973 us; speedup vs baseline: 1.8936x; 1.8936x over previous
//
#include <hip/hip_runtime.h>

// LDPC BP decoder, (3,6)-regular. 1 WG = 1 batch element, 1024 threads.
// Edge e (vn order) = 3v+j; c = e mod 8192; cn-order slot q = 6c+t, e = c+8192t.
// Thread owns CNs c = tid + 1024*i (i=0..7); messages f32 in registers
// (fully static-indexed -> true VGPRs, no scratch).
// Reference f32 op chain replicated literally; exp/log are lean f64
// implementations with ~2^-46 internal accuracy (~correctly rounded f32),
// valid on the restricted argument ranges this kernel produces.

constexpr int NUM_VNS  = 16384;
constexpr int NUM_ITER = 8;
constexpr float LLR_MAX  = 20.0f;
constexpr float PHI_MIN  = 8.5e-8f;
constexpr float PHI_MAX  = 16.635532f;

#define THREADS 1024

// exp(x) for x in [0, 16.64]; internal rel err ~2^-46.
__device__ __forceinline__ double lean_exp(double x) {
    double t = x * 1.4426950408889634;
    double k = __builtin_rint(t);
    double r = __builtin_fma(-k, 0.6931471805599453, x);
    r = __builtin_fma(-k, 2.3190468138462996e-17, r);
    double p = 1.0 / 39916800.0;                 // Taylor deg 11, |r|<=0.347
    p = __builtin_fma(p, r, 1.0 / 3628800.0);
    p = __builtin_fma(p, r, 1.0 / 362880.0);
    p = __builtin_fma(p, r, 1.0 / 40320.0);
    p = __builtin_fma(p, r, 1.0 / 5040.0);
    p = __builtin_fma(p, r, 1.0 / 720.0);
    p = __builtin_fma(p, r, 1.0 / 120.0);
    p = __builtin_fma(p, r, 1.0 / 24.0);
    p = __builtin_fma(p, r, 1.0 / 6.0);
    p = __builtin_fma(p, r, 0.5);
    p = __builtin_fma(p, r, 1.0);
    p = __builtin_fma(p, r, 1.0);
    int ik = (int)k;                              // k in [0,24]
    double s = __hiloint2double((1023 + ik) << 20, 0);
    return p * s;
}

// log(v) for v in [1e-7, 1.7e7], v an exact f32 value; rel err ~2^-46
// (degrades only where the result is tiny -> absolutely negligible).
__device__ __forceinline__ double lean_log(double v) {
    int hv = __double2hiint(v);
    int lv = __double2loint(v);
    int e  = (hv >> 20) - 1023;
    double m = __hiloint2double((hv & 0x000FFFFF) | 0x3FF00000, lv);
    if (m >= 1.4142135623730951) { m *= 0.5; e += 1; }   // m in [0.7071,1.4142)
    double t = m - 1.0;
    double d = t + 2.0;
    // u = t/d via f32-rcp seed + 2 f64 Newton steps (d in [1.7,2.42], benign)
    double r = (double)__builtin_amdgcn_rcpf((float)d);
    r = __builtin_fma(__builtin_fma(-d, r, 1.0), r, r);
    r = __builtin_fma(__builtin_fma(-d, r, 1.0), r, r);
    double u = t * r;
    double w = u * u;                             // w <= 0.0295
    double P = 2.0 / 17.0;                        // 2*artanh: deg 8 in w
    P = __builtin_fma(P, w, 2.0 / 15.0);
    P = __builtin_fma(P, w, 2.0 / 13.0);
    P = __builtin_fma(P, w, 2.0 / 11.0);
    P = __builtin_fma(P, w, 2.0 / 9.0);
    P = __builtin_fma(P, w, 2.0 / 7.0);
    P = __builtin_fma(P, w, 2.0 / 5.0);
    P = __builtin_fma(P, w, 2.0 / 3.0);
    P = __builtin_fma(P, w, 2.0);
    double lm = u * P;
    return __builtin_fma((double)e, 0.6931471805599453, lm);
}

// literal reference chain: clip; ex=f32(exp); a=ex+1, b=ex-1 in f32;
// la=f32(log a), lb=f32(log b); return la-lb.
__device__ __forceinline__ float phi_f(float xf) {
    xf = fminf(fmaxf(xf, PHI_MIN), PHI_MAX);
    float exf = (float)lean_exp((double)xf);
    float af = exf + 1.0f;
    float bf = exf - 1.0f;
    float la = (float)lean_log((double)af);
    float lb = (float)lean_log((double)bf);
    return la - lb;
}

__global__ __launch_bounds__(THREADS)
void ldpc_bp_kernel(const float* __restrict__ llr_ch, float* __restrict__ out)
{
    __shared__ float buf[24576];    // 96 KB: one half of the edges (3 t-blocks)
    __shared__ float vtot[NUM_VNS]; // 64 KB

    const int b   = blockIdx.x;
    const int tid = threadIdx.x;
    const float* __restrict__ llr_b = llr_ch + (size_t)b * NUM_VNS;

    float rllr[16];
#pragma unroll
    for (int k = 0; k < 16; ++k) {
        float x = llr_b[tid + THREADS * k];
        x = fminf(fmaxf(x, -LLR_MAX), LLR_MAX);
        rllr[k] = -x;
    }

    float msg[6][8];   // msg[t][i], edge e = (tid+1024i) + 8192t  (static idx only!)
#pragma unroll
    for (int t = 0; t < 6; ++t)
#pragma unroll
        for (int i = 0; i < 8; ++i) msg[t][i] = 0.0f;

    for (int iter = 0; iter <= NUM_ITER; ++iter) {
        // ---- A: stage t-blocks 0..2 into buf[e] ----
#pragma unroll
        for (int t = 0; t < 3; ++t)
#pragma unroll
            for (int i = 0; i < 8; ++i)
                buf[(t << 13) + tid + THREADS * i] = msg[t][i];
        __syncthreads();

        // ---- B: vtot for v in [0,8192), exact order ((m0+m1)+m2)+llr ----
#pragma unroll
        for (int k = 0; k < 8; ++k) {
            int v = tid + THREADS * k;
            int e = 3 * v;
            vtot[v] = ((buf[e] + buf[e + 1]) + buf[e + 2]) + rllr[k];
        }
        __syncthreads();

        // ---- C: stage t-blocks 3..5 ----
#pragma unroll
        for (int t = 0; t < 3; ++t)
#pragma unroll
            for (int i = 0; i < 8; ++i)
                buf[(t << 13) + tid + THREADS * i] = msg[t + 3][i];
        __syncthreads();

        // ---- D: vtot for v in [8192,16384) ----
#pragma unroll
        for (int k = 8; k < 16; ++k) {
            int v = tid + THREADS * k;
            int e = 3 * v - 24576;
            vtot[v] = ((buf[e] + buf[e + 1]) + buf[e + 2]) + rllr[k];
        }
        __syncthreads();

        if (iter == NUM_ITER) break;

        // ---- E: CN update, literal reference chain, fully unrolled ----
#pragma unroll
        for (int i = 0; i < 8; ++i) {
            int c = tid + THREADS * i;
            float mag[6];
            unsigned sb = 0u;
#pragma unroll
            for (int t = 0; t < 6; ++t) {
                int e = c + (t << 13);
                int v = (int)(((unsigned)e * 43691u) >> 17);   // e/3
                float m = vtot[v] - msg[t][i];                 // vn-extrinsic
                if (m < 0.0f) sb |= (1u << t);                 // sign(0) -> +1
                mag[t] = phi_f(fabsf(m));
            }
            float ms = ((((mag[0] + mag[1]) + mag[2]) + mag[3]) + mag[4]) + mag[5];
            unsigned all6 = __popc(sb) & 1u;
#pragma unroll
            for (int t = 0; t < 6; ++t) {
                float o = phi_f(ms - mag[t]);
                unsigned flip = all6 ^ ((sb >> t) & 1u);
                msg[t][i] = flip ? -o : o;
            }
        }
        __syncthreads();
    }

    // ---- marginalize: out[b][v] = -vtot[v] ----
#pragma unroll
    for (int k = 0; k < 16; ++k) {
        int v = tid + THREADS * k;
        out[(size_t)b * NUM_VNS + v] = -vtot[v];
    }
}

extern "C" void kernel_launch(void* const* d_in, const int* in_sizes, int n_in,
                              void* d_out, int out_size, void* d_ws, size_t ws_size,
                              hipStream_t stream) {
    const float* llr_ch = (const float*)d_in[0];
    float* out = (float*)d_out;
    ldpc_bp_kernel<<<dim3(128), dim3(THREADS), 0, stream>>>(llr_ch, out);
}

// Round 5
// 607.611 us; speedup vs baseline: 1.9010x; 1.0039x over previous
//
#include <hip/hip_runtime.h>

// LDPC BP decoder, (3,6)-regular. 1 WG = 1 batch element, 1024 threads.
// Edge e (vn order) = 3v+j; c = e mod 8192; cn-order slot q = 6c+t, e = c+8192t.
// Thread owns CNs c = tid + 1024*i (i=0..7); messages f32 in registers
// (fully static-indexed -> true VGPRs, no scratch).
// Reference f32 op chain replicated literally; exp/log are lean f64
// implementations with ~2^-46 internal accuracy (~correctly rounded f32).
//
// __launch_bounds__(1024, 4): LDS (160KB) pins us to ONE 16-wave WG per CU
// = 4 waves/EU; telling the backend so raises the VGPR budget 64 -> 128,
// eliminating the scratch spills seen in rounds 3/4 (WRITE_SIZE 225/54 MB).

constexpr int NUM_VNS  = 16384;
constexpr int NUM_ITER = 8;
constexpr float LLR_MAX  = 20.0f;
constexpr float PHI_MIN  = 8.5e-8f;
constexpr float PHI_MAX  = 16.635532f;

#define THREADS 1024

// exp(x) for x in [0, 16.64]; internal rel err ~2^-46.
__device__ __forceinline__ double lean_exp(double x) {
    double t = x * 1.4426950408889634;
    double k = __builtin_rint(t);
    double r = __builtin_fma(-k, 0.6931471805599453, x);
    r = __builtin_fma(-k, 2.3190468138462996e-17, r);
    double p = 1.0 / 39916800.0;                 // Taylor deg 11, |r|<=0.347
    p = __builtin_fma(p, r, 1.0 / 3628800.0);
    p = __builtin_fma(p, r, 1.0 / 362880.0);
    p = __builtin_fma(p, r, 1.0 / 40320.0);
    p = __builtin_fma(p, r, 1.0 / 5040.0);
    p = __builtin_fma(p, r, 1.0 / 720.0);
    p = __builtin_fma(p, r, 1.0 / 120.0);
    p = __builtin_fma(p, r, 1.0 / 24.0);
    p = __builtin_fma(p, r, 1.0 / 6.0);
    p = __builtin_fma(p, r, 0.5);
    p = __builtin_fma(p, r, 1.0);
    p = __builtin_fma(p, r, 1.0);
    int ik = (int)k;                              // k in [0,24]
    double s = __hiloint2double((1023 + ik) << 20, 0);
    return p * s;
}

// log(v) for v in [1e-7, 1.7e7], v an exact f32 value; rel err ~2^-46
// (degrades only where the result is tiny -> absolutely negligible).
__device__ __forceinline__ double lean_log(double v) {
    int hv = __double2hiint(v);
    int lv = __double2loint(v);
    int e  = (hv >> 20) - 1023;
    double m = __hiloint2double((hv & 0x000FFFFF) | 0x3FF00000, lv);
    if (m >= 1.4142135623730951) { m *= 0.5; e += 1; }   // m in [0.7071,1.4142)
    double t = m - 1.0;
    double d = t + 2.0;
    // u = t/d via f32-rcp seed + 2 f64 Newton steps (d in [1.7,2.42], benign)
    double r = (double)__builtin_amdgcn_rcpf((float)d);
    r = __builtin_fma(__builtin_fma(-d, r, 1.0), r, r);
    r = __builtin_fma(__builtin_fma(-d, r, 1.0), r, r);
    double u = t * r;
    double w = u * u;                             // w <= 0.0295
    double P = 2.0 / 17.0;                        // 2*artanh: deg 8 in w
    P = __builtin_fma(P, w, 2.0 / 15.0);
    P = __builtin_fma(P, w, 2.0 / 13.0);
    P = __builtin_fma(P, w, 2.0 / 11.0);
    P = __builtin_fma(P, w, 2.0 / 9.0);
    P = __builtin_fma(P, w, 2.0 / 7.0);
    P = __builtin_fma(P, w, 2.0 / 5.0);
    P = __builtin_fma(P, w, 2.0 / 3.0);
    P = __builtin_fma(P, w, 2.0);
    double lm = u * P;
    return __builtin_fma((double)e, 0.6931471805599453, lm);
}

// literal reference chain: clip; ex=f32(exp); a=ex+1, b=ex-1 in f32;
// la=f32(log a), lb=f32(log b); return la-lb.
__device__ __forceinline__ float phi_f(float xf) {
    xf = fminf(fmaxf(xf, PHI_MIN), PHI_MAX);
    float exf = (float)lean_exp((double)xf);
    float af = exf + 1.0f;
    float bf = exf - 1.0f;
    float la = (float)lean_log((double)af);
    float lb = (float)lean_log((double)bf);
    return la - lb;
}

__global__ __launch_bounds__(THREADS, 4)
void ldpc_bp_kernel(const float* __restrict__ llr_ch, float* __restrict__ out)
{
    __shared__ float buf[24576];    // 96 KB: one half of the edges (3 t-blocks)
    __shared__ float vtot[NUM_VNS]; // 64 KB

    const int b   = blockIdx.x;
    const int tid = threadIdx.x;
    const float* __restrict__ llr_b = llr_ch + (size_t)b * NUM_VNS;

    float rllr[16];
#pragma unroll
    for (int k = 0; k < 16; ++k) {
        float x = llr_b[tid + THREADS * k];
        x = fminf(fmaxf(x, -LLR_MAX), LLR_MAX);
        rllr[k] = -x;
    }

    float msg[6][8];   // msg[t][i], edge e = (tid+1024i) + 8192t  (static idx only!)
#pragma unroll
    for (int t = 0; t < 6; ++t)
#pragma unroll
        for (int i = 0; i < 8; ++i) msg[t][i] = 0.0f;

    for (int iter = 0; iter <= NUM_ITER; ++iter) {
        // ---- A: stage t-blocks 0..2 into buf[e] ----
#pragma unroll
        for (int t = 0; t < 3; ++t)
#pragma unroll
            for (int i = 0; i < 8; ++i)
                buf[(t << 13) + tid + THREADS * i] = msg[t][i];
        __syncthreads();

        // ---- B: vtot for v in [0,8192), exact order ((m0+m1)+m2)+llr ----
#pragma unroll
        for (int k = 0; k < 8; ++k) {
            int v = tid + THREADS * k;
            int e = 3 * v;
            vtot[v] = ((buf[e] + buf[e + 1]) + buf[e + 2]) + rllr[k];
        }
        __syncthreads();

        // ---- C: stage t-blocks 3..5 ----
#pragma unroll
        for (int t = 0; t < 3; ++t)
#pragma unroll
            for (int i = 0; i < 8; ++i)
                buf[(t << 13) + tid + THREADS * i] = msg[t + 3][i];
        __syncthreads();

        // ---- D: vtot for v in [8192,16384) ----
#pragma unroll
        for (int k = 8; k < 16; ++k) {
            int v = tid + THREADS * k;
            int e = 3 * v - 24576;
            vtot[v] = ((buf[e] + buf[e + 1]) + buf[e + 2]) + rllr[k];
        }
        __syncthreads();

        if (iter == NUM_ITER) break;

        // ---- E: CN update, literal reference chain, fully unrolled ----
#pragma unroll
        for (int i = 0; i < 8; ++i) {
            int c = tid + THREADS * i;
            float mag[6];
            unsigned sb = 0u;
#pragma unroll
            for (int t = 0; t < 6; ++t) {
                int e = c + (t << 13);
                int v = (int)(((unsigned)e * 43691u) >> 17);   // e/3
                float m = vtot[v] - msg[t][i];                 // vn-extrinsic
                if (m < 0.0f) sb |= (1u << t);                 // sign(0) -> +1
                mag[t] = phi_f(fabsf(m));
            }
            float ms = ((((mag[0] + mag[1]) + mag[2]) + mag[3]) + mag[4]) + mag[5];
            unsigned all6 = __popc(sb) & 1u;
#pragma unroll
            for (int t = 0; t < 6; ++t) {
                float o = phi_f(ms - mag[t]);
                unsigned flip = all6 ^ ((sb >> t) & 1u);
                msg[t][i] = flip ? -o : o;
            }
        }
        __syncthreads();
    }

    // ---- marginalize: out[b][v] = -vtot[v] ----
#pragma unroll
    for (int k = 0; k < 16; ++k) {
        int v = tid + THREADS * k;
        out[(size_t)b * NUM_VNS + v] = -vtot[v];
    }
}

extern "C" void kernel_launch(void* const* d_in, const int* in_sizes, int n_in,
                              void* d_out, int out_size, void* d_ws, size_t ws_size,
                              hipStream_t stream) {
    const float* llr_ch = (const float*)d_in[0];
    float* out = (float*)d_out;
    ldpc_bp_kernel<<<dim3(128), dim3(THREADS), 0, stream>>>(llr_ch, out);
}

// Round 6
// 605.652 us; speedup vs baseline: 1.9071x; 1.0032x over previous
//
#include <hip/hip_runtime.h>

// LDPC BP decoder, (3,6)-regular. 1 WG = 1 batch element, 1024 threads.
// Edge e (vn order) = 3v+j; c = e mod 8192; cn-order slot q = 6c+t, e = c+8192t.
// Thread owns CNs c = tid + 1024*i (i=0..7); messages f32 in registers
// (fully static-indexed). Reference f32 op chain replicated literally;
// exp/log are lean f64 implementations (~correctly rounded f32).
//
// amdgpu_waves_per_eu(4,4): LDS (160KB) pins us to ONE 16-wave WG per CU =
// 4 waves/EU. launch_bounds(1024,4) only sets the MIN; the RA still targeted
// 8 waves/EU -> 64 VGPRs -> ~12 spilled regs -> 47MB/side scratch traffic
// (r4/r5 counters). Pinning min=max=4 raises the budget to 128 VGPRs.

constexpr int NUM_VNS  = 16384;
constexpr int NUM_ITER = 8;
constexpr float LLR_MAX  = 20.0f;
constexpr float PHI_MIN  = 8.5e-8f;
constexpr float PHI_MAX  = 16.635532f;

#define THREADS 1024

// exp(x) for x in [0, 16.64]; internal rel err ~2^-46.
__device__ __forceinline__ double lean_exp(double x) {
    double t = x * 1.4426950408889634;
    double k = __builtin_rint(t);
    double r = __builtin_fma(-k, 0.6931471805599453, x);
    r = __builtin_fma(-k, 2.3190468138462996e-17, r);
    double p = 1.0 / 39916800.0;                 // Taylor deg 11, |r|<=0.347
    p = __builtin_fma(p, r, 1.0 / 3628800.0);
    p = __builtin_fma(p, r, 1.0 / 362880.0);
    p = __builtin_fma(p, r, 1.0 / 40320.0);
    p = __builtin_fma(p, r, 1.0 / 5040.0);
    p = __builtin_fma(p, r, 1.0 / 720.0);
    p = __builtin_fma(p, r, 1.0 / 120.0);
    p = __builtin_fma(p, r, 1.0 / 24.0);
    p = __builtin_fma(p, r, 1.0 / 6.0);
    p = __builtin_fma(p, r, 0.5);
    p = __builtin_fma(p, r, 1.0);
    p = __builtin_fma(p, r, 1.0);
    int ik = (int)k;                              // k in [0,24]
    double s = __hiloint2double((1023 + ik) << 20, 0);
    return p * s;
}

// log(v) for v in [1e-7, 1.7e7], v an exact f32 value; rel err ~2^-46.
__device__ __forceinline__ double lean_log(double v) {
    int hv = __double2hiint(v);
    int lv = __double2loint(v);
    int e  = (hv >> 20) - 1023;
    double m = __hiloint2double((hv & 0x000FFFFF) | 0x3FF00000, lv);
    if (m >= 1.4142135623730951) { m *= 0.5; e += 1; }   // m in [0.7071,1.4142)
    double t = m - 1.0;
    double d = t + 2.0;
    double r = (double)__builtin_amdgcn_rcpf((float)d);
    r = __builtin_fma(__builtin_fma(-d, r, 1.0), r, r);
    r = __builtin_fma(__builtin_fma(-d, r, 1.0), r, r);
    double u = t * r;
    double w = u * u;                             // w <= 0.0295
    double P = 2.0 / 17.0;                        // 2*artanh: deg 8 in w
    P = __builtin_fma(P, w, 2.0 / 15.0);
    P = __builtin_fma(P, w, 2.0 / 13.0);
    P = __builtin_fma(P, w, 2.0 / 11.0);
    P = __builtin_fma(P, w, 2.0 / 9.0);
    P = __builtin_fma(P, w, 2.0 / 7.0);
    P = __builtin_fma(P, w, 2.0 / 5.0);
    P = __builtin_fma(P, w, 2.0 / 3.0);
    P = __builtin_fma(P, w, 2.0);
    double lm = u * P;
    return __builtin_fma((double)e, 0.6931471805599453, lm);
}

// literal reference chain: clip; ex=f32(exp); a=ex+1, b=ex-1 in f32;
// la=f32(log a), lb=f32(log b); return la-lb.
__device__ __forceinline__ float phi_f(float xf) {
    xf = fminf(fmaxf(xf, PHI_MIN), PHI_MAX);
    float exf = (float)lean_exp((double)xf);
    float af = exf + 1.0f;
    float bf = exf - 1.0f;
    float la = (float)lean_log((double)af);
    float lb = (float)lean_log((double)bf);
    return la - lb;
}

__global__ __launch_bounds__(THREADS)
__attribute__((amdgpu_waves_per_eu(4, 4)))
void ldpc_bp_kernel(const float* __restrict__ llr_ch, float* __restrict__ out)
{
    __shared__ float buf[24576];    // 96 KB: one half of the edges (3 t-blocks)
    __shared__ float vtot[NUM_VNS]; // 64 KB

    const int b   = blockIdx.x;
    const int tid = threadIdx.x;
    const float* __restrict__ llr_b = llr_ch + (size_t)b * NUM_VNS;

    float rllr[16];
#pragma unroll
    for (int k = 0; k < 16; ++k) {
        float x = llr_b[tid + THREADS * k];
        x = fminf(fmaxf(x, -LLR_MAX), LLR_MAX);
        rllr[k] = -x;
    }

    float msg[6][8];   // msg[t][i], edge e = (tid+1024i) + 8192t  (static idx only!)
#pragma unroll
    for (int t = 0; t < 6; ++t)
#pragma unroll
        for (int i = 0; i < 8; ++i) msg[t][i] = 0.0f;

    for (int iter = 0; iter <= NUM_ITER; ++iter) {
        // ---- A: stage t-blocks 0..2 into buf[e] ----
#pragma unroll
        for (int t = 0; t < 3; ++t)
#pragma unroll
            for (int i = 0; i < 8; ++i)
                buf[(t << 13) + tid + THREADS * i] = msg[t][i];
        __syncthreads();

        // ---- B: vtot for v in [0,8192), exact order ((m0+m1)+m2)+llr ----
#pragma unroll
        for (int k = 0; k < 8; ++k) {
            int v = tid + THREADS * k;
            int e = 3 * v;
            vtot[v] = ((buf[e] + buf[e + 1]) + buf[e + 2]) + rllr[k];
        }
        __syncthreads();

        // ---- C: stage t-blocks 3..5 ----
#pragma unroll
        for (int t = 0; t < 3; ++t)
#pragma unroll
            for (int i = 0; i < 8; ++i)
                buf[(t << 13) + tid + THREADS * i] = msg[t + 3][i];
        __syncthreads();

        // ---- D: vtot for v in [8192,16384) ----
#pragma unroll
        for (int k = 8; k < 16; ++k) {
            int v = tid + THREADS * k;
            int e = 3 * v - 24576;
            vtot[v] = ((buf[e] + buf[e + 1]) + buf[e + 2]) + rllr[k];
        }
        __syncthreads();

        if (iter == NUM_ITER) break;

        // ---- E: CN update, literal reference chain, fully unrolled ----
#pragma unroll
        for (int i = 0; i < 8; ++i) {
            int c = tid + THREADS * i;
            float mag[6];
            unsigned sb = 0u;
#pragma unroll
            for (int t = 0; t < 6; ++t) {
                int e = c + (t << 13);
                int v = (int)(((unsigned)e * 43691u) >> 17);   // e/3
                float m = vtot[v] - msg[t][i];                 // vn-extrinsic
                if (m < 0.0f) sb |= (1u << t);                 // sign(0) -> +1
                mag[t] = phi_f(fabsf(m));
            }
            float ms = ((((mag[0] + mag[1]) + mag[2]) + mag[3]) + mag[4]) + mag[5];
            unsigned all6 = __popc(sb) & 1u;
#pragma unroll
            for (int t = 0; t < 6; ++t) {
                float o = phi_f(ms - mag[t]);
                unsigned flip = all6 ^ ((sb >> t) & 1u);
                msg[t][i] = flip ? -o : o;
            }
        }
        __syncthreads();
    }

    // ---- marginalize: out[b][v] = -vtot[v] ----
#pragma unroll
    for (int k = 0; k < 16; ++k) {
        int v = tid + THREADS * k;
        out[(size_t)b * NUM_VNS + v] = -vtot[v];
    }
}

extern "C" void kernel_launch(void* const* d_in, const int* in_sizes, int n_in,
                              void* d_out, int out_size, void* d_ws, size_t ws_size,
                              hipStream_t stream) {
    const float* llr_ch = (const float*)d_in[0];
    float* out = (float*)d_out;
    ldpc_bp_kernel<<<dim3(128), dim3(THREADS), 0, stream>>>(llr_ch, out);
}

// Round 7
// 591.409 us; speedup vs baseline: 1.9531x; 1.0241x over previous
//
#include <hip/hip_runtime.h>

// LDPC BP decoder, (3,6)-regular. 1 WG = 1 batch element, 1024 threads.
// Edge e (vn order) = 3v+j; c = e mod 8192; cn-order slot q = 6c+t, e = c+8192t.
// Thread owns CNs c = tid + 1024*i (i=0..7); messages f32 in registers
// (fully static-indexed). Reference f32 op chain replicated literally;
// exp/log are lean f64 implementations (>=2^-39 internal, ~CR f32).
//
// r4-r6 lesson: RA pins VGPR budget at 64 (attributes were no-ops; binary
// byte-identical). Fix = fit in 64: rllr[16] dropped (re-read llr from
// global, L2-resident; asm-LICM-fence), mag[6] folded into msg storage.

constexpr int NUM_VNS  = 16384;
constexpr int NUM_ITER = 8;
constexpr float LLR_MAX  = 20.0f;
constexpr float PHI_MIN  = 8.5e-8f;
constexpr float PHI_MAX  = 16.635532f;

#define THREADS 1024

// exp(x) for x in [0, 16.64]; internal rel err ~2^-42.
__device__ __forceinline__ double lean_exp(double x) {
    double t = x * 1.4426950408889634;
    double k = __builtin_rint(t);
    double r = __builtin_fma(-k, 0.6931471805599453, x);
    r = __builtin_fma(-k, 2.3190468138462996e-17, r);
    double p = 1.0 / 3628800.0;                  // Taylor deg 10, |r|<=0.347
    p = __builtin_fma(p, r, 1.0 / 362880.0);
    p = __builtin_fma(p, r, 1.0 / 40320.0);
    p = __builtin_fma(p, r, 1.0 / 5040.0);
    p = __builtin_fma(p, r, 1.0 / 720.0);
    p = __builtin_fma(p, r, 1.0 / 120.0);
    p = __builtin_fma(p, r, 1.0 / 24.0);
    p = __builtin_fma(p, r, 1.0 / 6.0);
    p = __builtin_fma(p, r, 0.5);
    p = __builtin_fma(p, r, 1.0);
    p = __builtin_fma(p, r, 1.0);
    int ik = (int)k;                              // k in [0,24]
    double s = __hiloint2double((1023 + ik) << 20, 0);
    return p * s;
}

// log(v) for v in [2^-23, 2^25], v an exact f32 value; abs err ~2^-40.
__device__ __forceinline__ double lean_log(double v) {
    int hv = __double2hiint(v);
    int lv = __double2loint(v);
    int e  = (hv >> 20) - 1023;
    double m = __hiloint2double((hv & 0x000FFFFF) | 0x3FF00000, lv);
    if (m >= 1.4142135623730951) { m *= 0.5; e += 1; }   // m in [0.7071,1.4142)
    double t = m - 1.0;
    double d = t + 2.0;
    // u = t/d via f32-rcp seed + 1 f64 Newton step (err ~seed^2 ~2^-45)
    double r = (double)__builtin_amdgcn_rcpf((float)d);
    r = __builtin_fma(__builtin_fma(-d, r, 1.0), r, r);
    double u = t * r;
    double w = u * u;                             // w <= 0.0295
    double P = 2.0 / 13.0;                        // 2*artanh: deg 6 in w
    P = __builtin_fma(P, w, 2.0 / 11.0);
    P = __builtin_fma(P, w, 2.0 / 9.0);
    P = __builtin_fma(P, w, 2.0 / 7.0);
    P = __builtin_fma(P, w, 2.0 / 5.0);
    P = __builtin_fma(P, w, 2.0 / 3.0);
    P = __builtin_fma(P, w, 2.0);
    double lm = u * P;
    return __builtin_fma((double)e, 0.6931471805599453, lm);
}

// literal reference chain: clip; ex=f32(exp); a=ex+1, b=ex-1 in f32;
// la=f32(log a), lb=f32(log b); return la-lb.
__device__ __forceinline__ float phi_f(float xf) {
    xf = fminf(fmaxf(xf, PHI_MIN), PHI_MAX);
    float exf = (float)lean_exp((double)xf);
    float af = exf + 1.0f;
    float bf = exf - 1.0f;
    float la = (float)lean_log((double)af);
    float lb = (float)lean_log((double)bf);
    return la - lb;
}

__global__ __launch_bounds__(THREADS)
void ldpc_bp_kernel(const float* __restrict__ llr_ch, float* __restrict__ out)
{
    __shared__ float buf[24576];    // 96 KB: one half of the edges (3 t-blocks)
    __shared__ float vtot[NUM_VNS]; // 64 KB

    const int b   = blockIdx.x;
    const int tid = threadIdx.x;
    const float* __restrict__ llr_b = llr_ch + (size_t)b * NUM_VNS;

    float msg[6][8];   // msg[t][i], edge e = (tid+1024i) + 8192t  (static idx only!)
#pragma unroll
    for (int t = 0; t < 6; ++t)
#pragma unroll
        for (int i = 0; i < 8; ++i) msg[t][i] = 0.0f;

    for (int iter = 0; iter <= NUM_ITER; ++iter) {
        // LICM fence: stop the compiler hoisting the llr loads into registers
        // (that would recreate the >64-VGPR pressure this round removes).
        unsigned long long lbase = (unsigned long long)llr_b;
        asm volatile("" : "+s"(lbase));
        const float* __restrict__ lp = (const float*)lbase;

        // ---- A: stage t-blocks 0..2 into buf[e] ----
#pragma unroll
        for (int t = 0; t < 3; ++t)
#pragma unroll
            for (int i = 0; i < 8; ++i)
                buf[(t << 13) + tid + THREADS * i] = msg[t][i];
        __syncthreads();

        // ---- B: vtot for v in [0,8192), exact order ((m0+m1)+m2)-x ----
#pragma unroll
        for (int k = 0; k < 8; ++k) {
            int v = tid + THREADS * k;
            float x = lp[v];
            x = fminf(fmaxf(x, -LLR_MAX), LLR_MAX);
            int e = 3 * v;
            vtot[v] = ((buf[e] + buf[e + 1]) + buf[e + 2]) - x;
        }
        __syncthreads();

        // ---- C: stage t-blocks 3..5 ----
#pragma unroll
        for (int t = 0; t < 3; ++t)
#pragma unroll
            for (int i = 0; i < 8; ++i)
                buf[(t << 13) + tid + THREADS * i] = msg[t + 3][i];
        __syncthreads();

        // ---- D: vtot for v in [8192,16384) ----
#pragma unroll
        for (int k = 8; k < 16; ++k) {
            int v = tid + THREADS * k;
            float x = lp[v];
            x = fminf(fmaxf(x, -LLR_MAX), LLR_MAX);
            int e = 3 * v - 24576;
            vtot[v] = ((buf[e] + buf[e + 1]) + buf[e + 2]) - x;
        }
        __syncthreads();

        if (iter == NUM_ITER) break;

        // ---- E: CN update, literal reference chain, fully unrolled.
        //      msg[t][i] is reused as mag storage (old msg dead after m). ----
#pragma unroll
        for (int i = 0; i < 8; ++i) {
            int c = tid + THREADS * i;
            unsigned sb = 0u;
#pragma unroll
            for (int t = 0; t < 6; ++t) {
                int e = c + (t << 13);
                int v = (int)(((unsigned)e * 43691u) >> 17);   // e/3
                float m = vtot[v] - msg[t][i];                 // vn-extrinsic
                if (m < 0.0f) sb |= (1u << t);                 // sign(0) -> +1
                msg[t][i] = phi_f(fabsf(m));                   // mag in place
            }
            float ms = ((((msg[0][i] + msg[1][i]) + msg[2][i]) + msg[3][i])
                        + msg[4][i]) + msg[5][i];
            unsigned all6 = __popc(sb) & 1u;
#pragma unroll
            for (int t = 0; t < 6; ++t) {
                float o = phi_f(ms - msg[t][i]);
                unsigned flip = all6 ^ ((sb >> t) & 1u);
                msg[t][i] = flip ? -o : o;
            }
        }
        __syncthreads();
    }

    // ---- marginalize: out[b][v] = -vtot[v] ----
#pragma unroll
    for (int k = 0; k < 16; ++k) {
        int v = tid + THREADS * k;
        out[(size_t)b * NUM_VNS + v] = -vtot[v];
    }
}

extern "C" void kernel_launch(void* const* d_in, const int* in_sizes, int n_in,
                              void* d_out, int out_size, void* d_ws, size_t ws_size,
                              hipStream_t stream) {
    const float* llr_ch = (const float*)d_in[0];
    float* out = (float*)d_out;
    ldpc_bp_kernel<<<dim3(128), dim3(THREADS), 0, stream>>>(llr_ch, out);
}